// Round 15
// baseline (206.919 us; speedup 1.0000x reference)
//
#include <hip/hip_runtime.h>
#include <math.h>

// Problem constants (from reference setup_inputs)
constexpr int B   = 32;
constexpr int C   = 256;
constexpr int HW  = 56 * 56;       // 3136
constexpr int HW4 = HW / 4;        // 784 float4 per (b,c) plane
constexpr int HID = 32;            // C / R, R=8
constexpr float LAMBDA_ALPHA = 1.0f;
constexpr float LAMBDA_BETA  = 0.5f;
constexpr int BDIM = 256;
constexpr int WPB  = BDIM / 64;            // 4 waves per block, one plane per wave
constexpr int FULL = HW4 / 64;             // 12 full rounds of 64 lanes
constexpr int TAIL = HW4 - FULL * 64;      // 16 remaining float4

// Native clang vector type — required by __builtin_nontemporal_store
// (HIP's float4 is a class, rejected by the builtin).
typedef float nfloat4 __attribute__((ext_vector_type(4)));

// ---------------------------------------------------------------------------
// Kernel 1: pool — one WAVE per (b,c) plane.  12 unrolled independent float4
// loads per lane, wave-internal shuffle reduce, zero barriers.
// ---------------------------------------------------------------------------
__global__ __launch_bounds__(BDIM) void pool_kernel(const float* __restrict__ x,
                                                    float* __restrict__ pooled) {
    const int lane = threadIdx.x & 63;
    const int wid  = threadIdx.x >> 6;
    const int bc   = blockIdx.x * WPB + wid;         // 0 .. 8191
    const float4* x4 = reinterpret_cast<const float4*>(x) + (size_t)bc * HW4;

    float s = 0.0f;
    #pragma unroll
    for (int r = 0; r < FULL; ++r) {
        float4 v = x4[r * 64 + lane];
        s += (v.x + v.y) + (v.z + v.w);
    }
    if (lane < TAIL) {
        float4 v = x4[FULL * 64 + lane];
        s += (v.x + v.y) + (v.z + v.w);
    }
    for (int off = 32; off > 0; off >>= 1) s += __shfl_down(s, off, 64);
    if (lane == 0) pooled[bc] = s * (1.0f / (float)HW);
}

// ---------------------------------------------------------------------------
// Kernel 2: coef — one block per batch row b.
//   Phase 1: h[b,:] = relu(pooled[b,:] @ fc1_w^T + fc1_b)  (32 units x 8 lanes)
//   Phase 2: 256 threads, one channel each: 4 dot-32 + sigmoid ->
//            coef[b*C+c] = (a0,b0,a1,b1)
// ---------------------------------------------------------------------------
__global__ __launch_bounds__(BDIM) void coef_kernel(const float* __restrict__ pooled,
                                                    const float* __restrict__ fc1_w,
                                                    const float* __restrict__ fc1_b,
                                                    const float* __restrict__ fc2_w,
                                                    const float* __restrict__ fc2_b,
                                                    float4* __restrict__ coef) {
    const int b   = blockIdx.x;
    const int tid = threadIdx.x;
    __shared__ float hsh[HID];

    // fc1: 32 hidden units, 8 lanes each (waves 0..3 cover units 0..31)
    {
        const int hh  = tid >> 3;
        const int sub = tid & 7;
        const float* pp = pooled + b * C;
        const float* pw = fc1_w + hh * C;
        float acc = 0.0f;
        #pragma unroll
        for (int q = 0; q < C / 8; ++q) {
            const int c = sub * (C / 8) + q;
            acc = fmaf(pp[c], pw[c], acc);
        }
        acc += __shfl_down(acc, 4, 64);
        acc += __shfl_down(acc, 2, 64);
        acc += __shfl_down(acc, 1, 64);
        if (sub == 0) hsh[hh] = fmaxf(acc + fc1_b[hh], 0.0f);
    }
    __syncthreads();

    // coef: one channel per thread
    {
        const int c = tid;                           // 0..255
        float o4[4];
        #pragma unroll
        for (int k = 0; k < 2; ++k) {
            #pragma unroll
            for (int e = 0; e < 2; ++e) {
                const int o = 2 * c + e;
                const float* w2 = fc2_w + (size_t)(k * 2 * C + o) * HID;
                float acc = fc2_b[k * 2 * C + o];
                #pragma unroll
                for (int q = 0; q < HID; ++q) acc = fmaf(w2[q], hsh[q], acc);
                const float d = 2.0f / (1.0f + expf(-acc)) - 1.0f;
                o4[k * 2 + e] = ((k == 0) ? 1.0f : 0.0f) +
                                ((e == 0) ? LAMBDA_ALPHA : LAMBDA_BETA) * d;
            }
        }
        coef[b * C + c] = make_float4(o4[0], o4[1], o4[2], o4[3]);
    }
}

// ---------------------------------------------------------------------------
// Kernel 3: apply — one WAVE per plane, pure stream.  One broadcast float4
// coefficient load, then 12 unrolled load/fma/store rounds; nontemporal
// stores (out is write-once; keep L3 for x).
// ---------------------------------------------------------------------------
__global__ __launch_bounds__(BDIM) void apply_kernel(const float* __restrict__ x,
                                                     const float4* __restrict__ coef,
                                                     float* __restrict__ out) {
    const int lane = threadIdx.x & 63;
    const int wid  = threadIdx.x >> 6;
    const int bc   = blockIdx.x * WPB + wid;         // 0 .. 8191

    const float4 cf = coef[bc];                      // wave-uniform broadcast
    const float4* x4 = reinterpret_cast<const float4*>(x) + (size_t)bc * HW4;
    nfloat4*      o4 = reinterpret_cast<nfloat4*>(out) + (size_t)bc * HW4;

    #pragma unroll
    for (int r = 0; r < FULL; ++r) {
        float4 v = x4[r * 64 + lane];
        nfloat4 rr;
        rr.x = fmaxf(fmaf(v.x, cf.x, cf.y), fmaf(v.x, cf.z, cf.w));
        rr.y = fmaxf(fmaf(v.y, cf.x, cf.y), fmaf(v.y, cf.z, cf.w));
        rr.z = fmaxf(fmaf(v.z, cf.x, cf.y), fmaf(v.z, cf.z, cf.w));
        rr.w = fmaxf(fmaf(v.w, cf.x, cf.y), fmaf(v.w, cf.z, cf.w));
        __builtin_nontemporal_store(rr, &o4[r * 64 + lane]);
    }
    if (lane < TAIL) {
        float4 v = x4[FULL * 64 + lane];
        nfloat4 rr;
        rr.x = fmaxf(fmaf(v.x, cf.x, cf.y), fmaf(v.x, cf.z, cf.w));
        rr.y = fmaxf(fmaf(v.y, cf.x, cf.y), fmaf(v.y, cf.z, cf.w));
        rr.z = fmaxf(fmaf(v.z, cf.x, cf.y), fmaf(v.z, cf.z, cf.w));
        rr.w = fmaxf(fmaf(v.w, cf.x, cf.y), fmaf(v.w, cf.z, cf.w));
        __builtin_nontemporal_store(rr, &o4[FULL * 64 + lane]);
    }
}

// ---------------------------------------------------------------------------
extern "C" void kernel_launch(void* const* d_in, const int* in_sizes, int n_in,
                              void* d_out, int out_size, void* d_ws, size_t ws_size,
                              hipStream_t stream) {
    const float* x     = (const float*)d_in[0];
    const float* fc1_w = (const float*)d_in[1];
    const float* fc1_b = (const float*)d_in[2];
    const float* fc2_w = (const float*)d_in[3];
    const float* fc2_b = (const float*)d_in[4];
    float* out = (float*)d_out;

    // workspace: pooled (B*C floats = 32 KB) | coef (B*C float4 = 128 KB)
    float*  pooled = (float*)d_ws;
    float4* coef   = (float4*)((char*)d_ws + (size_t)B * C * sizeof(float));

    pool_kernel<<<(B * C) / WPB, BDIM, 0, stream>>>(x, pooled);
    coef_kernel<<<B, BDIM, 0, stream>>>(pooled, fc1_w, fc1_b, fc2_w, fc2_b, coef);
    apply_kernel<<<(B * C) / WPB, BDIM, 0, stream>>>(x, coef, out);
}